// Round 6
// baseline (30.004 us; speedup 1.0000x reference)
//
#include <hip/hip_runtime.h>

// APLoss (r2d2 QAPLoss). B=2, H=W=32 -> N=M=1024/batch, D=128, 25 bins.
// u = 24*(1-sim); cumsum_k of triangular bins = clamp(k+1-u, 0, 1).
// 3 kernels: grid-sample -> fused sim+hist+AP (block = 8 q x all m) -> reduce.
// k_main: 1024 threads (16 waves) per block, 1 m per thread, for 4 waves/SIMD.

#define NQB 25

// DPP butterfly add over 16-lane rows (pure VALU, no LDS pipe).
template<int CTRL>
__device__ __forceinline__ float dppadd(float v) {
    int s = __builtin_amdgcn_update_dpp(0, __float_as_int(v), CTRL, 0xf, 0xf, true);
    return v + __int_as_float(s);
}
__device__ __forceinline__ float red16(float v) {
    v = dppadd<0xB1>(v);   // quad_perm xor1
    v = dppadd<0x4E>(v);   // quad_perm xor2
    v = dppadd<0x141>(v);  // row_half_mirror = xor7
    v = dppadd<0x140>(v);  // row_mirror      = xor15
    return v;              // every lane: its 16-lane-row sum
}

// ---- K1: bilinear grid-sample desc2 -> dbt[b][c][m]; block = (b,c) ---------
__global__ __launch_bounds__(256) void k_gs(const float* __restrict__ desc2,
                                            const float* __restrict__ grd,
                                            float* __restrict__ dbt)
{
    __shared__ float plane[1024];
    int r = blockIdx.x;            // b*128 + c
    int b = r >> 7;
    int tid = threadIdx.x;
    const float* src = desc2 + ((size_t)r << 10);
    *(float4*)&plane[tid * 4] = *(const float4*)&src[tid * 4];
    __syncthreads();
#pragma unroll
    for (int e = 0; e < 4; e++) {
        int m = tid + (e << 8);
        int pos = (b << 10) + m;
        float2 g = ((const float2*)grd)[pos];
        float fx = ((g.x + 1.f) * 32.f - 1.f) * 0.5f;
        float fy = ((g.y + 1.f) * 32.f - 1.f) * 0.5f;
        float x0f = floorf(fx), y0f = floorf(fy);
        float wx1 = fx - x0f, wy1 = fy - y0f;
        float wx0 = 1.f - wx1, wy0 = 1.f - wy1;
        int x0 = (int)x0f, y0 = (int)y0f;
        float acc = 0.f;
        if ((unsigned)y0 < 32u && (unsigned)x0 < 32u)
            acc += wy0 * wx0 * plane[(y0 << 5) + x0];
        if ((unsigned)y0 < 32u && (unsigned)(x0 + 1) < 32u)
            acc += wy0 * wx1 * plane[(y0 << 5) + x0 + 1];
        if ((unsigned)(y0 + 1) < 32u && (unsigned)x0 < 32u)
            acc += wy1 * wx0 * plane[((y0 + 1) << 5) + x0];
        if ((unsigned)(y0 + 1) < 32u && (unsigned)(x0 + 1) < 32u)
            acc += wy1 * wx1 * plane[((y0 + 1) << 5) + x0 + 1];
        dbt[((size_t)r << 10) + m] = acc;
    }
}

// ---- K2: fused sim + histogram + AP; block = 8 queries x ALL 1024 m --------
// 1024 threads (16 waves). Sim: thread owns m = tid; q-side via wave-uniform
// scalar loads. Hist: 2 waves per query (m-halves), lane l owns m = 512h+l+64e.
// AP in-block (8 records/query) -> 1 float per block.
__global__ __launch_bounds__(1024) void k_main(const float* __restrict__ desc1,
                                               const float* __restrict__ dbt,
                                               const int* __restrict__ label,
                                               float* __restrict__ appart)
{
    __shared__ float s[8][1024];     // sim tile (32 KB)
    __shared__ float CNs[8][8][NQB]; // per-query records
    __shared__ float CRs[8][8][NQB];
    __shared__ float apb[8];

    int tid = threadIdx.x;
    int qg0 = blockIdx.x << 3;      // global query base (b*1024 + n0)
    int b = qg0 >> 10;
    int n0 = qg0 & 1023;

    const float* d1 = desc1 + ((size_t)b << 17) + n0;  // q c-row: d1[c<<10 + q]
    const float* dp = dbt + ((size_t)b << 17) + tid;

    float a[8];
#pragma unroll
    for (int q = 0; q < 8; q++) a[q] = 0.f;

#pragma unroll 2
    for (int c = 0; c < 128; c += 4) {
        float d0 = dp[(size_t)(c + 0) << 10];
        float d1v = dp[(size_t)(c + 1) << 10];
        float d2 = dp[(size_t)(c + 2) << 10];
        float d3 = dp[(size_t)(c + 3) << 10];
#pragma unroll
        for (int q = 0; q < 8; q++) {
            // wave-uniform scalar loads: 8 consecutive floats per channel row
            float qa = d1[((size_t)(c + 0) << 10) + q];
            float qb = d1[((size_t)(c + 1) << 10) + q];
            float qc = d1[((size_t)(c + 2) << 10) + q];
            float qd = d1[((size_t)(c + 3) << 10) + q];
            a[q] = fmaf(qa, d0, fmaf(qb, d1v, fmaf(qc, d2, fmaf(qd, d3, a[q]))));
        }
    }
#pragma unroll
    for (int q = 0; q < 8; q++) s[q][tid] = a[q];
    __syncthreads();

    // histogram: wave w -> query w>>1, m-half w&1; lane l owns m = 512h+l+64e
    int w = tid >> 6, l = tid & 63;
    int q = w >> 1, h = w & 1;
    float CN[NQB], CR[NQB];
#pragma unroll
    for (int k = 0; k < NQB; k++) { CN[k] = 0.f; CR[k] = 0.f; }
    const float* sp = &s[q][(h << 9) + l];
    const int* lp = label + ((size_t)(qg0 + q) << 10) + (h << 9) + l;
#pragma unroll
    for (int e = 0; e < 8; e++) {
        float sv = sp[e << 6];
        float lf = (float)lp[(size_t)(e << 6)];
        float u = fmaf(-24.f, sv, 24.f);
#pragma unroll
        for (int k = 0; k < NQB; k++) {
            float t = fminf(fmaxf((float)(k + 1) - u, 0.f), 1.f);  // v_med3
            CN[k] += t;
            CR[k] = fmaf(lf, t, CR[k]);
        }
    }
#pragma unroll
    for (int k = 0; k < NQB; k++) { CN[k] = red16(CN[k]); CR[k] = red16(CR[k]); }
    if ((l & 15) == 0) {
        int rec = (h << 2) + (l >> 4);
#pragma unroll
        for (int k = 0; k < NQB; k++) { CNs[q][rec][k] = CN[k]; CRs[q][rec][k] = CR[k]; }
    }
    __syncthreads();

    // AP per query (8 threads), then block sum -> 1 float
    if (tid < 8) {
        float ap = 0.f, prev = 0.f;
#pragma unroll
        for (int k = 0; k < NQB; k++) {
            float cn = 0.f, cr = 0.f;
#pragma unroll
            for (int r = 0; r < 8; r++) { cn += CNs[tid][r][k]; cr += CRs[tid][r][k]; }
            float pr = cr / (1e-16f + cn);
            ap += pr * (cr - prev);
            prev = cr;
        }
        apb[tid] = ap / prev;
    }
    __syncthreads();
    if (tid == 0) {
        float v = 0.f;
#pragma unroll
        for (int q2 = 0; q2 < 8; q2++) v += apb[q2];
        appart[blockIdx.x] = v;
    }
}

// ---- K3: final reduce of per-block sums -> d_out ---------------------------
__global__ __launch_bounds__(256) void k_final(const float* __restrict__ appart,
                                               float* __restrict__ out,
                                               int nb, float invn)
{
    int tid = threadIdx.x;
    float v = (tid < nb) ? appart[tid] : 0.f;
    for (int off = 32; off; off >>= 1) v += __shfl_xor(v, off, 64);
    __shared__ float wsum[4];
    if ((tid & 63) == 0) wsum[tid >> 6] = v;
    __syncthreads();
    if (tid == 0) out[0] = (wsum[0] + wsum[1] + wsum[2] + wsum[3]) * invn;
}

extern "C" void kernel_launch(void* const* d_in, const int* in_sizes, int n_in,
                              void* d_out, int out_size, void* d_ws, size_t ws_size,
                              hipStream_t stream)
{
    const float* desc1 = (const float*)d_in[0];
    const float* desc2 = (const float*)d_in[1];
    // d_in[2] = reliability: unused by the reference output
    const float* grd   = (const float*)d_in[3];
    const int*   label = (const int*)d_in[4];

    int B = in_sizes[0] / (128 * 1024);
    int npos = B * 1024;

    float* ws = (float*)d_ws;
    float* dbt    = ws;                          // npos*128 floats ([b][c][m])
    float* appart = dbt + (size_t)npos * 128;    // npos/8 floats
    float* out = (float*)d_out;

    k_gs<<<B * 128, 256, 0, stream>>>(desc2, grd, dbt);
    k_main<<<npos / 8, 1024, 0, stream>>>(desc1, dbt, label, appart);
    k_final<<<1, 256, 0, stream>>>(appart, out, npos / 8, 1.f / (float)npos);
}